// Round 1
// baseline (839.410 us; speedup 1.0000x reference)
//
#include <hip/hip_runtime.h>
#include <hip/hip_bf16.h>

// LSTM: T=2048, B=512, INPUT=42, HIDDEN=64. Output uses ONLY batch element 511
// (reference indexes lstm_out[:, -1, :]). Single-row recurrence: 2048
// sequential steps of a 256x64 matvec + activations on ONE block.
//
// History: R3 compiler sank weight loads (VGPR=44); R4 "memory" clobber made
// RA spill instead (VGPR=52); R5 amdgpu_waves_per_eu(1,1) fixed residency
// (VGPR=132); R6 quad_perm DPP adds (pure VALU) + v_pk_fma_f32 -> 846.3us.
// R7 (this): (1) exp2 prescale — fold log2(e) into xproj output and W_hh
// registers so activations use v_exp_f32 (2^x) directly, removing 3 v_mul
// from the serial activation chain; (2) remove hstage staging + chunk flush —
// kc==0 lanes store hn straight to global (fire-and-forget, vmcnt never
// drained by the lgkm-only barrier), halving the pre-barrier ds-write drain.

#define T_STEPS 2048
#define BATCH   512
#define NIN     42
#define NH      64
#define NG      256   // 4*NH
#define CH      8     // scan steps per chunk
#define NCHUNK  (T_STEPS / CH)
#define XT      16    // timesteps per xproj block

#define LOG2E 1.44269504f

#if __has_builtin(__builtin_amdgcn_exp2f)
#define EXP2F __builtin_amdgcn_exp2f
#else
#define EXP2F exp2f
#endif

typedef float v2f __attribute__((ext_vector_type(2)));

// ---------------- Kernel 1: input projection for batch row 511 ----------------
// NOTE: output is pre-scaled by log2(e) so the scan's activations can use
// the native exp2 instruction without a multiply on the critical path.
__global__ __launch_bounds__(256) void xproj_kernel(
    const float* __restrict__ x, const float* __restrict__ W_ih,
    const float* __restrict__ b_ih, const float* __restrict__ b_hh,
    float* __restrict__ xp)
{
    const int g  = threadIdx.x;          // gate row 0..255
    const int t0 = blockIdx.x * XT;
    __shared__ float ws[NG * NIN];       // W_ih rows, packed [g][42]
    __shared__ float xs[XT][NIN];
    for (int i = threadIdx.x; i < NG * NIN; i += 256) ws[i] = W_ih[i];
    for (int i = threadIdx.x; i < XT * NIN; i += 256) {
        int tt = i / NIN, j = i % NIN;
        xs[tt][j] = x[((size_t)(t0 + tt) * BATCH + (BATCH - 1)) * NIN + j];
    }
    const float bias = b_ih[g] + b_hh[g];
    __syncthreads();
    const float* wr = &ws[g * NIN];
    for (int tt = 0; tt < XT; ++tt) {
        float s = bias;
#pragma unroll
        for (int i = 0; i < NIN; ++i) s += wr[i] * xs[tt][i];
        xp[(size_t)(t0 + tt) * NG + g] = s * LOG2E;
    }
}

// ---------------- Kernel 2: sequential LSTM scan (1 block, 256 threads) -------
// Barrier draining ONLY LDS ops (lgkmcnt); global loads/stores stay in flight.
__device__ __forceinline__ void wg_barrier_lgkm() {
    asm volatile("s_waitcnt lgkmcnt(0)\n\ts_barrier" ::: "memory");
}

__device__ __forceinline__ void pin2(v2f& v) {
    asm volatile("" : "+v"(v));
}

// xor-add within a quad via DPP quad_perm (pure VALU; no LDS pipe).
// xor1: perm [1,0,3,2] = 0xB1 ; xor2: perm [2,3,0,1] = 0x4E
template <int CTRL>
__device__ __forceinline__ float dpp_xadd(float v) {
    int s = __builtin_amdgcn_mov_dpp(__float_as_int(v), CTRL, 0xF, 0xF, true);
    return v + __int_as_float(s);
}

// Arguments below are pre-scaled by log2(e) (xs = x * log2e):
//   sigmoid(x) = 1/(1+2^(-xs))        tanh(x) = 1 - 2/(1+2^(2*xs))
__device__ __forceinline__ float sigmoid2(float xs) {
    return __builtin_amdgcn_rcpf(1.f + EXP2F(-xs));
}
__device__ __forceinline__ float tanh2(float xs) {
    return __builtin_fmaf(-2.f,
        __builtin_amdgcn_rcpf(1.f + EXP2F(xs + xs)), 1.f);
}
// c is in REAL units (activations output real values): tanh(c) needs one mul.
__device__ __forceinline__ float tanhc(float c) {
    return __builtin_fmaf(-2.f,
        __builtin_amdgcn_rcpf(1.f + EXP2F(c * (2.f * LOG2E))), 1.f);
}

__device__ __forceinline__ v2f fma2(v2f a, v2f b, v2f c) {
    return __builtin_elementwise_fma(a, b, c);   // -> v_pk_fma_f32
}

__global__ void
__attribute__((amdgpu_flat_work_group_size(256, 256), amdgpu_waves_per_eu(1, 1)))
lstm_scan_kernel(
    const float* __restrict__ W_hh, const float* __restrict__ xp,
    float* __restrict__ hout)
{
    const int lane = threadIdx.x;       // 0..255
    const int kc   = lane & 3;          // k-chunk (quad position)
    const int u    = lane >> 2;         // hidden unit

    __shared__ __align__(16) float hbuf[2][NH];        // h exchange (double buf)
    if (lane < NH) { hbuf[0][lane] = 0.f; hbuf[1][lane] = 0.f; }

    // Weights: W_hh[gate*64+u][kc*16 .. +16) as 8 v2f per gate = 64 VGPRs.
    // Scaled by log2(e) once at load so gate sums arrive exp2-ready.
    const v2f* W0 = (const v2f*)(W_hh + (0 * NH + u) * NH + kc * 16);
    const v2f* W1 = (const v2f*)(W_hh + (1 * NH + u) * NH + kc * 16);
    const v2f* W2 = (const v2f*)(W_hh + (2 * NH + u) * NH + kc * 16);
    const v2f* W3 = (const v2f*)(W_hh + (3 * NH + u) * NH + kc * 16);
    const v2f SC = {LOG2E, LOG2E};
    v2f w0a=W0[0]*SC, w0b=W0[1]*SC, w0c=W0[2]*SC, w0d=W0[3]*SC,
        w0e=W0[4]*SC, w0f=W0[5]*SC, w0g=W0[6]*SC, w0h=W0[7]*SC;
    v2f w1a=W1[0]*SC, w1b=W1[1]*SC, w1c=W1[2]*SC, w1d=W1[3]*SC,
        w1e=W1[4]*SC, w1f=W1[5]*SC, w1g=W1[6]*SC, w1h=W1[7]*SC;
    v2f w2a=W2[0]*SC, w2b=W2[1]*SC, w2c=W2[2]*SC, w2d=W2[3]*SC,
        w2e=W2[4]*SC, w2f=W2[5]*SC, w2g=W2[6]*SC, w2h=W2[7]*SC;
    v2f w3a=W3[0]*SC, w3b=W3[1]*SC, w3c=W3[2]*SC, w3d=W3[3]*SC,
        w3e=W3[4]*SC, w3f=W3[5]*SC, w3g=W3[6]*SC, w3h=W3[7]*SC;
    pin2(w0a); pin2(w0b); pin2(w0c); pin2(w0d); pin2(w0e); pin2(w0f); pin2(w0g); pin2(w0h);
    pin2(w1a); pin2(w1b); pin2(w1c); pin2(w1d); pin2(w1e); pin2(w1f); pin2(w1g); pin2(w1h);
    pin2(w2a); pin2(w2b); pin2(w2c); pin2(w2d); pin2(w2e); pin2(w2f); pin2(w2g); pin2(w2h);
    pin2(w3a); pin2(w3b); pin2(w3c); pin2(w3d); pin2(w3e); pin2(w3f); pin2(w3g); pin2(w3h);

    float c = 0.f;
    const int seed_off = kc * NH + u;   // my xp column
    float* __restrict__ hp = hout + u;  // my output column (kc==0 lanes only)

    float xq[CH];
#pragma unroll
    for (int tt = 0; tt < CH; ++tt) xq[tt] = xp[tt * NG + seed_off];

    wg_barrier_lgkm();                  // hbuf zeros visible

    for (int ch = 0; ch < NCHUNK; ++ch) {
        float xn[CH];
        if (ch + 1 < NCHUNK) {
#pragma unroll
            for (int tt = 0; tt < CH; ++tt)
                xn[tt] = xp[(size_t)(ch + 1) * (CH * NG) + tt * NG + seed_off];
        }

#pragma unroll
        for (int tt = 0; tt < CH; ++tt) {
            const int p = tt & 1;
            const float4* hb = (const float4*)hbuf[p];
            float4 hv0 = hb[kc * 4 + 0];
            float4 hv1 = hb[kc * 4 + 1];
            float4 hv2 = hb[kc * 4 + 2];
            float4 hv3 = hb[kc * 4 + 3];
            v2f h0 = {hv0.x, hv0.y}, h1 = {hv0.z, hv0.w};
            v2f h2 = {hv1.x, hv1.y}, h3 = {hv1.z, hv1.w};
            v2f h4 = {hv2.x, hv2.y}, h5 = {hv2.z, hv2.w};
            v2f h6 = {hv3.x, hv3.y}, h7 = {hv3.z, hv3.w};

            v2f a0 = {(kc == 0) ? xq[tt] : 0.f, 0.f};
            v2f a1 = {(kc == 1) ? xq[tt] : 0.f, 0.f};
            v2f a2 = {(kc == 2) ? xq[tt] : 0.f, 0.f};
            v2f a3 = {(kc == 3) ? xq[tt] : 0.f, 0.f};

            a0 = fma2(w0a, h0, a0); a0 = fma2(w0b, h1, a0);
            a0 = fma2(w0c, h2, a0); a0 = fma2(w0d, h3, a0);
            a0 = fma2(w0e, h4, a0); a0 = fma2(w0f, h5, a0);
            a0 = fma2(w0g, h6, a0); a0 = fma2(w0h, h7, a0);
            a1 = fma2(w1a, h0, a1); a1 = fma2(w1b, h1, a1);
            a1 = fma2(w1c, h2, a1); a1 = fma2(w1d, h3, a1);
            a1 = fma2(w1e, h4, a1); a1 = fma2(w1f, h5, a1);
            a1 = fma2(w1g, h6, a1); a1 = fma2(w1h, h7, a1);
            a2 = fma2(w2a, h0, a2); a2 = fma2(w2b, h1, a2);
            a2 = fma2(w2c, h2, a2); a2 = fma2(w2d, h3, a2);
            a2 = fma2(w2e, h4, a2); a2 = fma2(w2f, h5, a2);
            a2 = fma2(w2g, h6, a2); a2 = fma2(w2h, h7, a2);
            a3 = fma2(w3a, h0, a3); a3 = fma2(w3b, h1, a3);
            a3 = fma2(w3c, h2, a3); a3 = fma2(w3d, h3, a3);
            a3 = fma2(w3e, h4, a3); a3 = fma2(w3f, h5, a3);
            a3 = fma2(w3g, h6, a3); a3 = fma2(w3h, h7, a3);

            float s0 = a0.x + a0.y;
            float s1 = a1.x + a1.y;
            float s2 = a2.x + a2.y;
            float s3 = a3.x + a3.y;

            // quad butterfly via DPP (xor1 then xor2) — pure VALU
            s0 = dpp_xadd<0xB1>(s0); s1 = dpp_xadd<0xB1>(s1);
            s2 = dpp_xadd<0xB1>(s2); s3 = dpp_xadd<0xB1>(s3);
            s0 = dpp_xadd<0x4E>(s0); s1 = dpp_xadd<0x4E>(s1);
            s2 = dpp_xadd<0x4E>(s2); s3 = dpp_xadd<0x4E>(s3);

            // gates i, f, g, o (sums pre-scaled by log2e -> exp2 native)
            float i_ = sigmoid2(s0);
            float f_ = sigmoid2(s1);
            float g_ = tanh2(s2);
            float o_ = sigmoid2(s3);

            c = f_ * c + i_ * g_;
            float hn = o_ * tanhc(c);

            if (kc == 0) {
                hbuf[1 - p][u] = hn;
                // fire-and-forget global store; vmcnt is NOT drained by the
                // lgkm-only barrier, so this never sits on the critical path.
                hp[(size_t)(ch * CH + tt) * NH] = hn;
            }
            wg_barrier_lgkm();
        }

#pragma unroll
        for (int tt = 0; tt < CH; ++tt) xq[tt] = xn[tt];
    }
}

// ---------------- Kernel 3: output projection out[t] = W_out @ h_t + b_out ----
__global__ __launch_bounds__(256) void outproj_kernel(
    const float* __restrict__ hout, const float* __restrict__ W_out,
    const float* __restrict__ b_out, float* __restrict__ out)
{
    int idx = blockIdx.x * blockDim.x + threadIdx.x;   // T*2
    if (idx >= T_STEPS * 2) return;
    int t = idx >> 1, o = idx & 1;
    const float* hr = hout + (size_t)t * NH;
    const float* wr = W_out + o * NH;
    float s = b_out[o];
#pragma unroll
    for (int j = 0; j < NH; ++j) s += hr[j] * wr[j];
    out[t * 2 + o] = s;
}

extern "C" void kernel_launch(void* const* d_in, const int* in_sizes, int n_in,
                              void* d_out, int out_size, void* d_ws, size_t ws_size,
                              hipStream_t stream) {
    const float* x     = (const float*)d_in[0];
    const float* W_ih  = (const float*)d_in[1];
    const float* W_hh  = (const float*)d_in[2];
    const float* b_ih  = (const float*)d_in[3];
    const float* b_hh  = (const float*)d_in[4];
    const float* W_out = (const float*)d_in[5];
    const float* b_out = (const float*)d_in[6];
    float* out = (float*)d_out;

    // workspace layout: xp (T*256 floats) | hout (T*64 floats)  = 2.5 MB
    float* xp   = (float*)d_ws;
    float* hout = xp + (size_t)T_STEPS * NG;

    xproj_kernel<<<T_STEPS / XT, 256, 0, stream>>>(x, W_ih, b_ih, b_hh, xp);
    lstm_scan_kernel<<<1, 256, 0, stream>>>(W_hh, xp, hout);
    outproj_kernel<<<(T_STEPS * 2 + 255) / 256, 256, 0, stream>>>(hout, W_out, b_out, out);
}

// Round 2
// 758.561 us; speedup vs baseline: 1.1066x; 1.1066x over previous
//
#include <hip/hip_runtime.h>
#include <hip/hip_bf16.h>

// LSTM: T=2048, B=512, INPUT=42, HIDDEN=64. Output uses ONLY batch element 511
// (reference indexes lstm_out[:, -1, :]). Single-row recurrence: 2048
// sequential steps of a 256x64 matvec + activations on ONE block.
//
// History: R3 compiler sank weight loads (VGPR=44); R4 "memory" clobber made
// RA spill instead (VGPR=52); R5 amdgpu_waves_per_eu(1,1) fixed residency
// (VGPR=132); R6 quad_perm DPP adds + v_pk_fma_f32 -> 846.3us total.
// R7 exp2-prescale + direct global h store -> 839.4us (scan 623.9us; counters:
// VALUBusy ~46% of active CU -> half issue, half latency/sync; 10 trans
// ops/step were 4x redundant across each quad).
// R8 (this): distribute activations across the quad. Transpose-reduce via
// cndmask-selected DPP sends (lane kc ends with gate-kc total), each lane
// applies only its own gate's activation (unified fma/rcp/exp2 form with
// per-lane hoisted constants), xp seed folded into the exp2 argument
// (precomputed per chunk), gates gathered to lane kc==0 with 3 DPP movs.
// Trans ops/step: 10 -> 4. Butterfly+seed issue: ~28 -> ~24 insts.

#define T_STEPS 2048
#define BATCH   512
#define NIN     42
#define NH      64
#define NG      256   // 4*NH
#define CH      8     // scan steps per chunk
#define NCHUNK  (T_STEPS / CH)
#define XT      16    // timesteps per xproj block

#define LOG2E 1.44269504f

#if __has_builtin(__builtin_amdgcn_exp2f)
#define EXP2F __builtin_amdgcn_exp2f
#else
#define EXP2F exp2f
#endif

typedef float v2f __attribute__((ext_vector_type(2)));

// ---------------- Kernel 1: input projection for batch row 511 ----------------
// Output pre-scaled by log2(e) so the scan's activations use native exp2.
__global__ __launch_bounds__(256) void xproj_kernel(
    const float* __restrict__ x, const float* __restrict__ W_ih,
    const float* __restrict__ b_ih, const float* __restrict__ b_hh,
    float* __restrict__ xp)
{
    const int g  = threadIdx.x;          // gate row 0..255
    const int t0 = blockIdx.x * XT;
    __shared__ float ws[NG * NIN];       // W_ih rows, packed [g][42]
    __shared__ float xs[XT][NIN];
    for (int i = threadIdx.x; i < NG * NIN; i += 256) ws[i] = W_ih[i];
    for (int i = threadIdx.x; i < XT * NIN; i += 256) {
        int tt = i / NIN, j = i % NIN;
        xs[tt][j] = x[((size_t)(t0 + tt) * BATCH + (BATCH - 1)) * NIN + j];
    }
    const float bias = b_ih[g] + b_hh[g];
    __syncthreads();
    const float* wr = &ws[g * NIN];
    for (int tt = 0; tt < XT; ++tt) {
        float s = bias;
#pragma unroll
        for (int i = 0; i < NIN; ++i) s += wr[i] * xs[tt][i];
        xp[(size_t)(t0 + tt) * NG + g] = s * LOG2E;
    }
}

// ---------------- Kernel 2: sequential LSTM scan (1 block, 256 threads) -------
// Barrier draining ONLY LDS ops (lgkmcnt); global loads/stores stay in flight.
__device__ __forceinline__ void wg_barrier_lgkm() {
    asm volatile("s_waitcnt lgkmcnt(0)\n\ts_barrier" ::: "memory");
}

__device__ __forceinline__ void pin2(v2f& v) {
    asm volatile("" : "+v"(v));
}

// quad_perm DPP mov (pure VALU; no LDS pipe).
// xor1: perm [1,0,3,2] = 0xB1 ; xor2: perm [2,3,0,1] = 0x4E
template <int CTRL>
__device__ __forceinline__ float dpp_mov(float v) {
    return __int_as_float(
        __builtin_amdgcn_mov_dpp(__float_as_int(v), CTRL, 0xF, 0xF, true));
}

__device__ __forceinline__ v2f fma2(v2f a, v2f b, v2f c) {
    return __builtin_elementwise_fma(a, b, c);   // -> v_pk_fma_f32
}

__global__ void
__attribute__((amdgpu_flat_work_group_size(256, 256), amdgpu_waves_per_eu(1, 1)))
lstm_scan_kernel(
    const float* __restrict__ W_hh, const float* __restrict__ xp,
    float* __restrict__ hout)
{
    const int lane = threadIdx.x;       // 0..255
    const int kc   = lane & 3;          // k-chunk (quad position) == owned gate
    const int u    = lane >> 2;         // hidden unit

    __shared__ __align__(16) float hbuf[2][NH];        // h exchange (double buf)
    if (lane < NH) { hbuf[0][lane] = 0.f; hbuf[1][lane] = 0.f; }

    // Per-lane activation constants (hoisted): gate kc.
    //   sigmoid(xs) = rcp(1+exp2(-xs))          -> m=-1, A=1,  B=0
    //   tanh(xs)    = fma(-2, rcp(1+exp2(2xs)), 1) -> m= 2, A=-2, B=1
    const bool istanh = (kc == 2);
    const float gm = istanh ?  2.f : -1.f;
    const float gA = istanh ? -2.f :  1.f;
    const float gB = istanh ?  1.f :  0.f;
    const bool lo = (kc & 1) != 0;
    const bool hi = (kc & 2) != 0;

    // Weights: W_hh[gate*64+u][kc*16 .. +16) as 8 v2f per gate = 64 VGPRs.
    // Scaled by log2(e) once at load so gate sums arrive exp2-ready.
    const v2f* W0 = (const v2f*)(W_hh + (0 * NH + u) * NH + kc * 16);
    const v2f* W1 = (const v2f*)(W_hh + (1 * NH + u) * NH + kc * 16);
    const v2f* W2 = (const v2f*)(W_hh + (2 * NH + u) * NH + kc * 16);
    const v2f* W3 = (const v2f*)(W_hh + (3 * NH + u) * NH + kc * 16);
    const v2f SC = {LOG2E, LOG2E};
    v2f w0a=W0[0]*SC, w0b=W0[1]*SC, w0c=W0[2]*SC, w0d=W0[3]*SC,
        w0e=W0[4]*SC, w0f=W0[5]*SC, w0g=W0[6]*SC, w0h=W0[7]*SC;
    v2f w1a=W1[0]*SC, w1b=W1[1]*SC, w1c=W1[2]*SC, w1d=W1[3]*SC,
        w1e=W1[4]*SC, w1f=W1[5]*SC, w1g=W1[6]*SC, w1h=W1[7]*SC;
    v2f w2a=W2[0]*SC, w2b=W2[1]*SC, w2c=W2[2]*SC, w2d=W2[3]*SC,
        w2e=W2[4]*SC, w2f=W2[5]*SC, w2g=W2[6]*SC, w2h=W2[7]*SC;
    v2f w3a=W3[0]*SC, w3b=W3[1]*SC, w3c=W3[2]*SC, w3d=W3[3]*SC,
        w3e=W3[4]*SC, w3f=W3[5]*SC, w3g=W3[6]*SC, w3h=W3[7]*SC;
    pin2(w0a); pin2(w0b); pin2(w0c); pin2(w0d); pin2(w0e); pin2(w0f); pin2(w0g); pin2(w0h);
    pin2(w1a); pin2(w1b); pin2(w1c); pin2(w1d); pin2(w1e); pin2(w1f); pin2(w1g); pin2(w1h);
    pin2(w2a); pin2(w2b); pin2(w2c); pin2(w2d); pin2(w2e); pin2(w2f); pin2(w2g); pin2(w2h);
    pin2(w3a); pin2(w3b); pin2(w3c); pin2(w3d); pin2(w3e); pin2(w3f); pin2(w3g); pin2(w3h);

    float c = 0.f;
    const int seed_off = kc * NH + u;   // my xp column (gate kc, unit u)
    float* __restrict__ hp = hout + u;  // my output column (kc==0 lanes only)

    // xp seed pre-folded by per-lane gate multiplier m (off the critical path).
    float mxq[CH];
#pragma unroll
    for (int tt = 0; tt < CH; ++tt) mxq[tt] = gm * xp[tt * NG + seed_off];

    wg_barrier_lgkm();                  // hbuf zeros visible

    for (int ch = 0; ch < NCHUNK; ++ch) {
        float xn[CH];
        if (ch + 1 < NCHUNK) {
#pragma unroll
            for (int tt = 0; tt < CH; ++tt)
                xn[tt] = xp[(size_t)(ch + 1) * (CH * NG) + tt * NG + seed_off];
        }

#pragma unroll
        for (int tt = 0; tt < CH; ++tt) {
            const int p = tt & 1;
            const float4* hb = (const float4*)hbuf[p];
            float4 hv0 = hb[kc * 4 + 0];
            float4 hv1 = hb[kc * 4 + 1];
            float4 hv2 = hb[kc * 4 + 2];
            float4 hv3 = hb[kc * 4 + 3];
            v2f h0 = {hv0.x, hv0.y}, h1 = {hv0.z, hv0.w};
            v2f h2 = {hv1.x, hv1.y}, h3 = {hv1.z, hv1.w};
            v2f h4 = {hv2.x, hv2.y}, h5 = {hv2.z, hv2.w};
            v2f h6 = {hv3.x, hv3.y}, h7 = {hv3.z, hv3.w};

            v2f a0 = {0.f, 0.f}, a1 = {0.f, 0.f}, a2 = {0.f, 0.f}, a3 = {0.f, 0.f};

            a0 = fma2(w0a, h0, a0); a0 = fma2(w0b, h1, a0);
            a0 = fma2(w0c, h2, a0); a0 = fma2(w0d, h3, a0);
            a0 = fma2(w0e, h4, a0); a0 = fma2(w0f, h5, a0);
            a0 = fma2(w0g, h6, a0); a0 = fma2(w0h, h7, a0);
            a1 = fma2(w1a, h0, a1); a1 = fma2(w1b, h1, a1);
            a1 = fma2(w1c, h2, a1); a1 = fma2(w1d, h3, a1);
            a1 = fma2(w1e, h4, a1); a1 = fma2(w1f, h5, a1);
            a1 = fma2(w1g, h6, a1); a1 = fma2(w1h, h7, a1);
            a2 = fma2(w2a, h0, a2); a2 = fma2(w2b, h1, a2);
            a2 = fma2(w2c, h2, a2); a2 = fma2(w2d, h3, a2);
            a2 = fma2(w2e, h4, a2); a2 = fma2(w2f, h5, a2);
            a2 = fma2(w2g, h6, a2); a2 = fma2(w2h, h7, a2);
            a3 = fma2(w3a, h0, a3); a3 = fma2(w3b, h1, a3);
            a3 = fma2(w3c, h2, a3); a3 = fma2(w3d, h3, a3);
            a3 = fma2(w3e, h4, a3); a3 = fma2(w3f, h5, a3);
            a3 = fma2(w3g, h6, a3); a3 = fma2(w3h, h7, a3);

            float p0 = a0.x + a0.y;
            float p1 = a1.x + a1.y;
            float p2 = a2.x + a2.y;
            float p3 = a3.x + a3.y;

            // Transpose-reduce across the quad: lane kc ends with the TOTAL
            // for gate kc (2 DPP rounds, cndmask-selected sends).
            // Round 1 (xor1): pair-sums of gate (kc&1) and gate 2|(kc&1).
            float k01 = lo ? p1 : p0;
            float s01 = lo ? p0 : p1;
            float k23 = lo ? p3 : p2;
            float s23 = lo ? p2 : p3;
            float r0 = k01 + dpp_mov<0xB1>(s01);
            float r1 = k23 + dpp_mov<0xB1>(s23);
            // Round 2 (xor2): full sum of gate kc.
            float kf = hi ? r1 : r0;
            float sf = hi ? r0 : r1;
            float s  = kf + dpp_mov<0x4E>(sf);

            // Own-gate activation; xp seed folded into the exp2 argument.
            float e = EXP2F(__builtin_fmaf(gm, s, mxq[tt]));
            float r = __builtin_amdgcn_rcpf(1.f + e);
            float v = __builtin_fmaf(gA, r, gB);   // lane0:i 1:f 2:g 3:o

            // Gather the 4 activated gates to lane kc==0 (3 DPP movs).
            float w  = dpp_mov<0xB1>(v);   // lane0: f   (lane2: o)
            float g0 = dpp_mov<0x4E>(v);   // lane0: g
            float oo = dpp_mov<0x4E>(w);   // lane0: o

            float t   = v * g0;            // i*g
            float p2o = -2.f * oo;         // off-path for the tail fma
            c = __builtin_fmaf(w, c, t);   // c = f*c + i*g
            float e2 = EXP2F(c * (2.f * LOG2E));
            float rr = __builtin_amdgcn_rcpf(1.f + e2);
            float hn = __builtin_fmaf(p2o, rr, oo);  // o*tanh(c)

            if (kc == 0) {
                hbuf[1 - p][u] = hn;
                // fire-and-forget global store; vmcnt is NOT drained by the
                // lgkm-only barrier, so this never sits on the critical path.
                hp[(size_t)(ch * CH + tt) * NH] = hn;
            }
            wg_barrier_lgkm();
        }

#pragma unroll
        for (int tt = 0; tt < CH; ++tt) mxq[tt] = gm * xn[tt];
    }
}

// ---------------- Kernel 3: output projection out[t] = W_out @ h_t + b_out ----
__global__ __launch_bounds__(256) void outproj_kernel(
    const float* __restrict__ hout, const float* __restrict__ W_out,
    const float* __restrict__ b_out, float* __restrict__ out)
{
    int idx = blockIdx.x * blockDim.x + threadIdx.x;   // T*2
    if (idx >= T_STEPS * 2) return;
    int t = idx >> 1, o = idx & 1;
    const float* hr = hout + (size_t)t * NH;
    const float* wr = W_out + o * NH;
    float s = b_out[o];
#pragma unroll
    for (int j = 0; j < NH; ++j) s += hr[j] * wr[j];
    out[t * 2 + o] = s;
}

extern "C" void kernel_launch(void* const* d_in, const int* in_sizes, int n_in,
                              void* d_out, int out_size, void* d_ws, size_t ws_size,
                              hipStream_t stream) {
    const float* x     = (const float*)d_in[0];
    const float* W_ih  = (const float*)d_in[1];
    const float* W_hh  = (const float*)d_in[2];
    const float* b_ih  = (const float*)d_in[3];
    const float* b_hh  = (const float*)d_in[4];
    const float* W_out = (const float*)d_in[5];
    const float* b_out = (const float*)d_in[6];
    float* out = (float*)d_out;

    // workspace layout: xp (T*256 floats) | hout (T*64 floats)  = 2.5 MB
    float* xp   = (float*)d_ws;
    float* hout = xp + (size_t)T_STEPS * NG;

    xproj_kernel<<<T_STEPS / XT, 256, 0, stream>>>(x, W_ih, b_ih, b_hh, xp);
    lstm_scan_kernel<<<1, 256, 0, stream>>>(W_hh, xp, hout);
    outproj_kernel<<<(T_STEPS * 2 + 255) / 256, 256, 0, stream>>>(hout, W_out, b_out, out);
}

// Round 3
// 722.537 us; speedup vs baseline: 1.1618x; 1.0499x over previous
//
#include <hip/hip_runtime.h>
#include <hip/hip_bf16.h>

// LSTM: T=2048, B=512, INPUT=42, HIDDEN=64. Output uses ONLY batch element 511
// (reference indexes lstm_out[:, -1, :]). Single-row recurrence: 2048
// sequential steps of a 256x64 matvec + activations on ONE block.
//
// History: R5 amdgpu_waves_per_eu(1,1) residency (VGPR=132); R6 quad_perm DPP
// + v_pk_fma_f32 -> 846us; R7 exp2-prescale + direct global h store -> 758.6us
// (scan 541.4); R8 distributed per-gate activations across the quad (trans
// 10->4/step).
// R9 (this): XOR-slot weight permutation — slot r of lane j accumulates gate
// r^j (weights pre-permuted+pre-scaled at load, incl. per-destination-gate
// multiplier gm and log2e). The transpose-reduce becomes 3 uniform DPP-adds
// with ZERO cndmask selects; the xp seed folds into a0.x's init (only lane
// j's slot 0 routes gate j), so e=exp2(s) directly; c kept pre-scaled by
// 2*log2e so its exp2 needs no multiply. ~12 fewer VALU insts/step, ~30-40
// cyc off the serial chain.

#define T_STEPS 2048
#define BATCH   512
#define NIN     42
#define NH      64
#define NG      256   // 4*NH
#define CH      8     // scan steps per chunk
#define NCHUNK  (T_STEPS / CH)
#define XT      16    // timesteps per xproj block

#define LOG2E  1.44269504f
#define TWOL2E 2.88539008f

#if __has_builtin(__builtin_amdgcn_exp2f)
#define EXP2F __builtin_amdgcn_exp2f
#else
#define EXP2F exp2f
#endif

typedef float v2f __attribute__((ext_vector_type(2)));

// ---------------- Kernel 1: input projection for batch row 511 ----------------
// Output pre-scaled by log2(e) so the scan's activations use native exp2.
__global__ __launch_bounds__(256) void xproj_kernel(
    const float* __restrict__ x, const float* __restrict__ W_ih,
    const float* __restrict__ b_ih, const float* __restrict__ b_hh,
    float* __restrict__ xp)
{
    const int g  = threadIdx.x;          // gate row 0..255
    const int t0 = blockIdx.x * XT;
    __shared__ float ws[NG * NIN];       // W_ih rows, packed [g][42]
    __shared__ float xs[XT][NIN];
    for (int i = threadIdx.x; i < NG * NIN; i += 256) ws[i] = W_ih[i];
    for (int i = threadIdx.x; i < XT * NIN; i += 256) {
        int tt = i / NIN, j = i % NIN;
        xs[tt][j] = x[((size_t)(t0 + tt) * BATCH + (BATCH - 1)) * NIN + j];
    }
    const float bias = b_ih[g] + b_hh[g];
    __syncthreads();
    const float* wr = &ws[g * NIN];
    for (int tt = 0; tt < XT; ++tt) {
        float s = bias;
#pragma unroll
        for (int i = 0; i < NIN; ++i) s += wr[i] * xs[tt][i];
        xp[(size_t)(t0 + tt) * NG + g] = s * LOG2E;
    }
}

// ---------------- Kernel 2: sequential LSTM scan (1 block, 256 threads) -------
// Barrier draining ONLY LDS ops (lgkmcnt); global loads/stores stay in flight.
__device__ __forceinline__ void wg_barrier_lgkm() {
    asm volatile("s_waitcnt lgkmcnt(0)\n\ts_barrier" ::: "memory");
}

__device__ __forceinline__ void pin2(v2f& v) {
    asm volatile("" : "+v"(v));
}

// quad_perm DPP mov (pure VALU; no LDS pipe).
// xor1: perm [1,0,3,2] = 0xB1 ; xor2: perm [2,3,0,1] = 0x4E
template <int CTRL>
__device__ __forceinline__ float dpp_mov(float v) {
    return __int_as_float(
        __builtin_amdgcn_mov_dpp(__float_as_int(v), CTRL, 0xF, 0xF, true));
}

__device__ __forceinline__ v2f fma2(v2f a, v2f b, v2f c) {
    return __builtin_elementwise_fma(a, b, c);   // -> v_pk_fma_f32
}

__global__ void
__attribute__((amdgpu_flat_work_group_size(256, 256), amdgpu_waves_per_eu(1, 1)))
lstm_scan_kernel(
    const float* __restrict__ W_hh, const float* __restrict__ xp,
    float* __restrict__ hout)
{
    const int lane = threadIdx.x;       // 0..255
    const int kc   = lane & 3;          // quad position == owned gate == k-chunk
    const int u    = lane >> 2;         // hidden unit

    __shared__ __align__(16) float hbuf[2][NH];        // h exchange (double buf)
    if (lane < NH) { hbuf[0][lane] = 0.f; hbuf[1][lane] = 0.f; }

    // Per-lane activation constants for OWN gate kc:
    //   sigmoid: act = rcp(1+e), e=2^(-raw*l2e)   -> gm=-1, gA=1,  gB=0
    //   tanh   : act = 1-2*rcp(1+e), e=2^(2raw*l2e)-> gm= 2, gA=-2, gB=1
    const bool istanh = (kc == 2);
    const float gm = istanh ?  2.f : -1.f;
    const float gA = istanh ? -2.f :  1.f;
    const float gB = istanh ?  1.f :  0.f;

    // XOR-slot permutation: slot r of lane kc accumulates gate (r^kc), k-chunk
    // kc. Weight scale absorbs log2e and the destination gate's gm.
    const int g0i = 0 ^ kc, g1i = 1 ^ kc, g2i = 2 ^ kc, g3i = 3 ^ kc;
    const float f0 = LOG2E * ((g0i == 2) ? 2.f : -1.f);
    const float f1 = LOG2E * ((g1i == 2) ? 2.f : -1.f);
    const float f2 = LOG2E * ((g2i == 2) ? 2.f : -1.f);
    const float f3 = LOG2E * ((g3i == 2) ? 2.f : -1.f);
    const v2f SC0 = {f0, f0}, SC1 = {f1, f1}, SC2 = {f2, f2}, SC3 = {f3, f3};

    const v2f* W0 = (const v2f*)(W_hh + ((size_t)g0i * NH + u) * NH + kc * 16);
    const v2f* W1 = (const v2f*)(W_hh + ((size_t)g1i * NH + u) * NH + kc * 16);
    const v2f* W2 = (const v2f*)(W_hh + ((size_t)g2i * NH + u) * NH + kc * 16);
    const v2f* W3 = (const v2f*)(W_hh + ((size_t)g3i * NH + u) * NH + kc * 16);
    v2f w0a=W0[0]*SC0, w0b=W0[1]*SC0, w0c=W0[2]*SC0, w0d=W0[3]*SC0,
        w0e=W0[4]*SC0, w0f=W0[5]*SC0, w0g=W0[6]*SC0, w0h=W0[7]*SC0;
    v2f w1a=W1[0]*SC1, w1b=W1[1]*SC1, w1c=W1[2]*SC1, w1d=W1[3]*SC1,
        w1e=W1[4]*SC1, w1f=W1[5]*SC1, w1g=W1[6]*SC1, w1h=W1[7]*SC1;
    v2f w2a=W2[0]*SC2, w2b=W2[1]*SC2, w2c=W2[2]*SC2, w2d=W2[3]*SC2,
        w2e=W2[4]*SC2, w2f=W2[5]*SC2, w2g=W2[6]*SC2, w2h=W2[7]*SC2;
    v2f w3a=W3[0]*SC3, w3b=W3[1]*SC3, w3c=W3[2]*SC3, w3d=W3[3]*SC3,
        w3e=W3[4]*SC3, w3f=W3[5]*SC3, w3g=W3[6]*SC3, w3h=W3[7]*SC3;
    pin2(w0a); pin2(w0b); pin2(w0c); pin2(w0d); pin2(w0e); pin2(w0f); pin2(w0g); pin2(w0h);
    pin2(w1a); pin2(w1b); pin2(w1c); pin2(w1d); pin2(w1e); pin2(w1f); pin2(w1g); pin2(w1h);
    pin2(w2a); pin2(w2b); pin2(w2c); pin2(w2d); pin2(w2e); pin2(w2f); pin2(w2g); pin2(w2h);
    pin2(w3a); pin2(w3b); pin2(w3c); pin2(w3d); pin2(w3e); pin2(w3f); pin2(w3g); pin2(w3h);

    float C = 0.f;                      // cell state pre-scaled by 2*log2e
    const int seed_off = kc * NH + u;   // my xp column (gate kc, unit u)
    float* __restrict__ hp = hout + u;  // my output column (kc==0 lanes only)

    // xp seed pre-folded by own gate multiplier gm (off the critical path).
    float mxq[CH];
#pragma unroll
    for (int tt = 0; tt < CH; ++tt) mxq[tt] = gm * xp[tt * NG + seed_off];

    wg_barrier_lgkm();                  // hbuf zeros visible

    for (int ch = 0; ch < NCHUNK; ++ch) {
        float xn[CH];
        if (ch + 1 < NCHUNK) {
#pragma unroll
            for (int tt = 0; tt < CH; ++tt)
                xn[tt] = xp[(size_t)(ch + 1) * (CH * NG) + tt * NG + seed_off];
        }

#pragma unroll
        for (int tt = 0; tt < CH; ++tt) {
            const int p = tt & 1;
            const float4* hb = (const float4*)hbuf[p];
            float4 hv0 = hb[kc * 4 + 0];
            float4 hv1 = hb[kc * 4 + 1];
            float4 hv2 = hb[kc * 4 + 2];
            float4 hv3 = hb[kc * 4 + 3];
            v2f h0 = {hv0.x, hv0.y}, h1 = {hv0.z, hv0.w};
            v2f h2 = {hv1.x, hv1.y}, h3 = {hv1.z, hv1.w};
            v2f h4 = {hv2.x, hv2.y}, h5 = {hv2.z, hv2.w};
            v2f h6 = {hv3.x, hv3.y}, h7 = {hv3.z, hv3.w};

            // Seed lands in slot 0 only: slot 0 of lane kc routes gate kc,
            // counted exactly once across the quad.
            v2f a0 = {mxq[tt], 0.f};
            v2f a1 = {0.f, 0.f}, a2 = {0.f, 0.f}, a3 = {0.f, 0.f};

            a0 = fma2(w0a, h0, a0); a0 = fma2(w0b, h1, a0);
            a0 = fma2(w0c, h2, a0); a0 = fma2(w0d, h3, a0);
            a0 = fma2(w0e, h4, a0); a0 = fma2(w0f, h5, a0);
            a0 = fma2(w0g, h6, a0); a0 = fma2(w0h, h7, a0);
            a1 = fma2(w1a, h0, a1); a1 = fma2(w1b, h1, a1);
            a1 = fma2(w1c, h2, a1); a1 = fma2(w1d, h3, a1);
            a1 = fma2(w1e, h4, a1); a1 = fma2(w1f, h5, a1);
            a1 = fma2(w1g, h6, a1); a1 = fma2(w1h, h7, a1);
            a2 = fma2(w2a, h0, a2); a2 = fma2(w2b, h1, a2);
            a2 = fma2(w2c, h2, a2); a2 = fma2(w2d, h3, a2);
            a2 = fma2(w2e, h4, a2); a2 = fma2(w2f, h5, a2);
            a2 = fma2(w2g, h6, a2); a2 = fma2(w2h, h7, a2);
            a3 = fma2(w3a, h0, a3); a3 = fma2(w3b, h1, a3);
            a3 = fma2(w3c, h2, a3); a3 = fma2(w3d, h3, a3);
            a3 = fma2(w3e, h4, a3); a3 = fma2(w3f, h5, a3);
            a3 = fma2(w3g, h6, a3); a3 = fma2(w3h, h7, a3);

            float p0 = a0.x + a0.y;
            float p1 = a1.x + a1.y;
            float p2 = a2.x + a2.y;
            float p3 = a3.x + a3.y;

            // Uniform transpose-reduce (no selects): lane j ends with the
            // FULL pre-scaled sum of gate j.
            float r0 = p0 + dpp_mov<0xB1>(p1);
            float r1 = p2 + dpp_mov<0xB1>(p3);
            float s  = r0 + dpp_mov<0x4E>(r1);

            // Own-gate activation; arg already includes gm, log2e, and seed.
            float e = EXP2F(s);
            float r = __builtin_amdgcn_rcpf(1.f + e);
            float v = __builtin_fmaf(gA, r, gB);   // lane0:i 1:f 2:g 3:o

            // Gather the 4 activated gates to lane kc==0 (3 DPP movs).
            float w  = dpp_mov<0xB1>(v);   // lane0: f
            float g0 = dpp_mov<0x4E>(v);   // lane0: g
            float oo = dpp_mov<0x4E>(w);   // lane0: o

            float vs  = v * TWOL2E;        // 2*log2e*i (ready before gathers)
            float t2  = vs * g0;           // 2*log2e*(i*g)
            float p2o = -2.f * oo;         // off-path for the tail fma
            C = __builtin_fmaf(w, C, t2);  // C = f*C + 2l2e*(i*g)
            float e2 = EXP2F(C);           // = e^(2c)
            float rr = __builtin_amdgcn_rcpf(1.f + e2);
            float hn = __builtin_fmaf(p2o, rr, oo);  // o*tanh(c)

            if (kc == 0) {
                hbuf[1 - p][u] = hn;
                // fire-and-forget global store; vmcnt is NOT drained by the
                // lgkm-only barrier, so this never sits on the critical path.
                hp[(size_t)(ch * CH + tt) * NH] = hn;
            }
            wg_barrier_lgkm();
        }

#pragma unroll
        for (int tt = 0; tt < CH; ++tt) mxq[tt] = gm * xn[tt];
    }
}

// ---------------- Kernel 3: output projection out[t] = W_out @ h_t + b_out ----
__global__ __launch_bounds__(256) void outproj_kernel(
    const float* __restrict__ hout, const float* __restrict__ W_out,
    const float* __restrict__ b_out, float* __restrict__ out)
{
    int idx = blockIdx.x * blockDim.x + threadIdx.x;   // T*2
    if (idx >= T_STEPS * 2) return;
    int t = idx >> 1, o = idx & 1;
    const float* hr = hout + (size_t)t * NH;
    const float* wr = W_out + o * NH;
    float s = b_out[o];
#pragma unroll
    for (int j = 0; j < NH; ++j) s += hr[j] * wr[j];
    out[t * 2 + o] = s;
}

extern "C" void kernel_launch(void* const* d_in, const int* in_sizes, int n_in,
                              void* d_out, int out_size, void* d_ws, size_t ws_size,
                              hipStream_t stream) {
    const float* x     = (const float*)d_in[0];
    const float* W_ih  = (const float*)d_in[1];
    const float* W_hh  = (const float*)d_in[2];
    const float* b_ih  = (const float*)d_in[3];
    const float* b_hh  = (const float*)d_in[4];
    const float* W_out = (const float*)d_in[5];
    const float* b_out = (const float*)d_in[6];
    float* out = (float*)d_out;

    // workspace layout: xp (T*256 floats) | hout (T*64 floats)  = 2.5 MB
    float* xp   = (float*)d_ws;
    float* hout = xp + (size_t)T_STEPS * NG;

    xproj_kernel<<<T_STEPS / XT, 256, 0, stream>>>(x, W_ih, b_ih, b_hh, xp);
    lstm_scan_kernel<<<1, 256, 0, stream>>>(W_hh, xp, hout);
    outproj_kernel<<<(T_STEPS * 2 + 255) / 256, 256, 0, stream>>>(hout, W_out, b_out, out);
}

// Round 4
// 722.518 us; speedup vs baseline: 1.1618x; 1.0000x over previous
//
#include <hip/hip_runtime.h>
#include <hip/hip_bf16.h>

// LSTM: T=2048, B=512, INPUT=42, HIDDEN=64. Output uses ONLY batch element 511
// (reference indexes lstm_out[:, -1, :]). Single-row recurrence: 2048
// sequential steps of a 256x64 matvec + activations on ONE block.
//
// History: R5 waves_per_eu(1,1) residency; R6 quad DPP + pk_fma -> 846us;
// R7 exp2-prescale + direct global h store -> 758.6 (scan 541); R8 distributed
// per-gate activations (trans 10->4/step) -> 722.5 (scan 505); R9 XOR-slot
// weight permutation (select-free transpose-reduce, seed folded into acc init).
// R10 (this): tail-level squeeze — (1) oo gathered directly via quad_perm
// [3,2,1,0] (0x1B) so all 3 gathers depend only on v (-1 chain level);
// (2) 2*log2e folded into lane0's activation consts (v = 2l2e*i), deleting
// the vs mul; (3) per-gate multiplier gm folded into xproj's row scale,
// deleting the per-chunk mxq muls; (4) CH 8->16 halves chunk-boundary cost.

#define T_STEPS 2048
#define BATCH   512
#define NIN     42
#define NH      64
#define NG      256   // 4*NH
#define CH      16    // scan steps per chunk
#define NCHUNK  (T_STEPS / CH)
#define XT      16    // timesteps per xproj block

#define LOG2E  1.44269504f
#define TWOL2E 2.88539008f

#if __has_builtin(__builtin_amdgcn_exp2f)
#define EXP2F __builtin_amdgcn_exp2f
#else
#define EXP2F exp2f
#endif

typedef float v2f __attribute__((ext_vector_type(2)));

// ---------------- Kernel 1: input projection for batch row 511 ----------------
// Output pre-scaled by log2(e) AND the destination gate's exp2 multiplier gm
// (gm = +2 for the tanh gate g, -1 for sigmoid gates i,f,o), so the scan's
// seeds are exp2-ready with zero scan-side multiplies.
__global__ __launch_bounds__(256) void xproj_kernel(
    const float* __restrict__ x, const float* __restrict__ W_ih,
    const float* __restrict__ b_ih, const float* __restrict__ b_hh,
    float* __restrict__ xp)
{
    const int g  = threadIdx.x;          // gate row 0..255
    const int t0 = blockIdx.x * XT;
    __shared__ float ws[NG * NIN];       // W_ih rows, packed [g][42]
    __shared__ float xs[XT][NIN];
    for (int i = threadIdx.x; i < NG * NIN; i += 256) ws[i] = W_ih[i];
    for (int i = threadIdx.x; i < XT * NIN; i += 256) {
        int tt = i / NIN, j = i % NIN;
        xs[tt][j] = x[((size_t)(t0 + tt) * BATCH + (BATCH - 1)) * NIN + j];
    }
    const float bias = b_ih[g] + b_hh[g];
    // gate index = g>>6 (PyTorch order i,f,g,o); gate 2 is tanh.
    const float sc = ((g >> 6) == 2) ? (2.f * LOG2E) : (-LOG2E);
    __syncthreads();
    const float* wr = &ws[g * NIN];
    for (int tt = 0; tt < XT; ++tt) {
        float s = bias;
#pragma unroll
        for (int i = 0; i < NIN; ++i) s += wr[i] * xs[tt][i];
        xp[(size_t)(t0 + tt) * NG + g] = s * sc;
    }
}

// ---------------- Kernel 2: sequential LSTM scan (1 block, 256 threads) -------
// Barrier draining ONLY LDS ops (lgkmcnt); global loads/stores stay in flight.
__device__ __forceinline__ void wg_barrier_lgkm() {
    asm volatile("s_waitcnt lgkmcnt(0)\n\ts_barrier" ::: "memory");
}

__device__ __forceinline__ void pin2(v2f& v) {
    asm volatile("" : "+v"(v));
}

// quad_perm DPP mov (pure VALU; no LDS pipe).
// xor1: [1,0,3,2]=0xB1 ; xor2: [2,3,0,1]=0x4E ; xor3: [3,2,1,0]=0x1B
template <int CTRL>
__device__ __forceinline__ float dpp_mov(float v) {
    return __int_as_float(
        __builtin_amdgcn_mov_dpp(__float_as_int(v), CTRL, 0xF, 0xF, true));
}

__device__ __forceinline__ v2f fma2(v2f a, v2f b, v2f c) {
    return __builtin_elementwise_fma(a, b, c);   // -> v_pk_fma_f32
}

__global__ void
__attribute__((amdgpu_flat_work_group_size(256, 256), amdgpu_waves_per_eu(1, 1)))
lstm_scan_kernel(
    const float* __restrict__ W_hh, const float* __restrict__ xp,
    float* __restrict__ hout)
{
    const int lane = threadIdx.x;       // 0..255
    const int kc   = lane & 3;          // quad position == owned gate == k-chunk
    const int u    = lane >> 2;         // hidden unit

    __shared__ __align__(16) float hbuf[2][NH];        // h exchange (double buf)
    if (lane < NH) { hbuf[0][lane] = 0.f; hbuf[1][lane] = 0.f; }

    // Per-lane activation constants for OWN gate kc (raw sums arrive already
    // scaled for exp2):
    //   i (kc=0): v = 2l2e * sigmoid = 2l2e*rcp(1+e)   -> gA=2l2e, gB=0
    //   f,o     : v = sigmoid = rcp(1+e)               -> gA=1,    gB=0
    //   g (kc=2): v = tanh = fma(-2, rcp(1+e), 1)      -> gA=-2,   gB=1
    const bool istanh = (kc == 2);
    const float gA = istanh ? -2.f : ((kc == 0) ? TWOL2E : 1.f);
    const float gB = istanh ? 1.f : 0.f;

    // XOR-slot permutation: slot r of lane kc accumulates gate (r^kc), k-chunk
    // kc. Weight scale absorbs log2e and the destination gate's gm.
    const int g0i = 0 ^ kc, g1i = 1 ^ kc, g2i = 2 ^ kc, g3i = 3 ^ kc;
    const float f0 = LOG2E * ((g0i == 2) ? 2.f : -1.f);
    const float f1 = LOG2E * ((g1i == 2) ? 2.f : -1.f);
    const float f2 = LOG2E * ((g2i == 2) ? 2.f : -1.f);
    const float f3 = LOG2E * ((g3i == 2) ? 2.f : -1.f);
    const v2f SC0 = {f0, f0}, SC1 = {f1, f1}, SC2 = {f2, f2}, SC3 = {f3, f3};

    const v2f* W0 = (const v2f*)(W_hh + ((size_t)g0i * NH + u) * NH + kc * 16);
    const v2f* W1 = (const v2f*)(W_hh + ((size_t)g1i * NH + u) * NH + kc * 16);
    const v2f* W2 = (const v2f*)(W_hh + ((size_t)g2i * NH + u) * NH + kc * 16);
    const v2f* W3 = (const v2f*)(W_hh + ((size_t)g3i * NH + u) * NH + kc * 16);
    v2f w0a=W0[0]*SC0, w0b=W0[1]*SC0, w0c=W0[2]*SC0, w0d=W0[3]*SC0,
        w0e=W0[4]*SC0, w0f=W0[5]*SC0, w0g=W0[6]*SC0, w0h=W0[7]*SC0;
    v2f w1a=W1[0]*SC1, w1b=W1[1]*SC1, w1c=W1[2]*SC1, w1d=W1[3]*SC1,
        w1e=W1[4]*SC1, w1f=W1[5]*SC1, w1g=W1[6]*SC1, w1h=W1[7]*SC1;
    v2f w2a=W2[0]*SC2, w2b=W2[1]*SC2, w2c=W2[2]*SC2, w2d=W2[3]*SC2,
        w2e=W2[4]*SC2, w2f=W2[5]*SC2, w2g=W2[6]*SC2, w2h=W2[7]*SC2;
    v2f w3a=W3[0]*SC3, w3b=W3[1]*SC3, w3c=W3[2]*SC3, w3d=W3[3]*SC3,
        w3e=W3[4]*SC3, w3f=W3[5]*SC3, w3g=W3[6]*SC3, w3h=W3[7]*SC3;
    pin2(w0a); pin2(w0b); pin2(w0c); pin2(w0d); pin2(w0e); pin2(w0f); pin2(w0g); pin2(w0h);
    pin2(w1a); pin2(w1b); pin2(w1c); pin2(w1d); pin2(w1e); pin2(w1f); pin2(w1g); pin2(w1h);
    pin2(w2a); pin2(w2b); pin2(w2c); pin2(w2d); pin2(w2e); pin2(w2f); pin2(w2g); pin2(w2h);
    pin2(w3a); pin2(w3b); pin2(w3c); pin2(w3d); pin2(w3e); pin2(w3f); pin2(w3g); pin2(w3h);

    float C = 0.f;                      // cell state pre-scaled by 2*log2e
    const int seed_off = kc * NH + u;   // my xp column (gate kc, unit u)
    float* __restrict__ hp = hout + u;  // my output column (kc==0 lanes only)

    // Seeds arrive fully pre-scaled from xproj (log2e * own-gate gm).
    float xq[CH];
#pragma unroll
    for (int tt = 0; tt < CH; ++tt) xq[tt] = xp[tt * NG + seed_off];

    wg_barrier_lgkm();                  // hbuf zeros visible

    for (int ch = 0; ch < NCHUNK; ++ch) {
        float xn[CH];
        if (ch + 1 < NCHUNK) {
#pragma unroll
            for (int tt = 0; tt < CH; ++tt)
                xn[tt] = xp[(size_t)(ch + 1) * (CH * NG) + tt * NG + seed_off];
        }

#pragma unroll
        for (int tt = 0; tt < CH; ++tt) {
            const int p = tt & 1;
            const float4* hb = (const float4*)hbuf[p];
            float4 hv0 = hb[kc * 4 + 0];
            float4 hv1 = hb[kc * 4 + 1];
            float4 hv2 = hb[kc * 4 + 2];
            float4 hv3 = hb[kc * 4 + 3];
            v2f h0 = {hv0.x, hv0.y}, h1 = {hv0.z, hv0.w};
            v2f h2 = {hv1.x, hv1.y}, h3 = {hv1.z, hv1.w};
            v2f h4 = {hv2.x, hv2.y}, h5 = {hv2.z, hv2.w};
            v2f h6 = {hv3.x, hv3.y}, h7 = {hv3.z, hv3.w};

            // Seed lands in slot 0 only: slot 0 of lane kc routes gate kc,
            // counted exactly once across the quad.
            v2f a0 = {xq[tt], 0.f};
            v2f a1 = {0.f, 0.f}, a2 = {0.f, 0.f}, a3 = {0.f, 0.f};

            a0 = fma2(w0a, h0, a0); a0 = fma2(w0b, h1, a0);
            a0 = fma2(w0c, h2, a0); a0 = fma2(w0d, h3, a0);
            a0 = fma2(w0e, h4, a0); a0 = fma2(w0f, h5, a0);
            a0 = fma2(w0g, h6, a0); a0 = fma2(w0h, h7, a0);
            a1 = fma2(w1a, h0, a1); a1 = fma2(w1b, h1, a1);
            a1 = fma2(w1c, h2, a1); a1 = fma2(w1d, h3, a1);
            a1 = fma2(w1e, h4, a1); a1 = fma2(w1f, h5, a1);
            a1 = fma2(w1g, h6, a1); a1 = fma2(w1h, h7, a1);
            a2 = fma2(w2a, h0, a2); a2 = fma2(w2b, h1, a2);
            a2 = fma2(w2c, h2, a2); a2 = fma2(w2d, h3, a2);
            a2 = fma2(w2e, h4, a2); a2 = fma2(w2f, h5, a2);
            a2 = fma2(w2g, h6, a2); a2 = fma2(w2h, h7, a2);
            a3 = fma2(w3a, h0, a3); a3 = fma2(w3b, h1, a3);
            a3 = fma2(w3c, h2, a3); a3 = fma2(w3d, h3, a3);
            a3 = fma2(w3e, h4, a3); a3 = fma2(w3f, h5, a3);
            a3 = fma2(w3g, h6, a3); a3 = fma2(w3h, h7, a3);

            float p0 = a0.x + a0.y;
            float p1 = a1.x + a1.y;
            float p2 = a2.x + a2.y;
            float p3 = a3.x + a3.y;

            // Uniform transpose-reduce (no selects): lane j ends with the
            // FULL pre-scaled sum of gate j.
            float r0 = p0 + dpp_mov<0xB1>(p1);
            float r1 = p2 + dpp_mov<0xB1>(p3);
            float s  = r0 + dpp_mov<0x4E>(r1);

            // Own-gate activation; lane0 directly produces 2l2e*i.
            float e = EXP2F(s);
            float r = __builtin_amdgcn_rcpf(1.f + e);
            float v = __builtin_fmaf(gA, r, gB);   // lane0:2l2e*i 1:f 2:g 3:o

            // Gather to lane kc==0 — all three depend only on v (parallel).
            float w  = dpp_mov<0xB1>(v);   // lane0: f
            float g0 = dpp_mov<0x4E>(v);   // lane0: g
            float oo = dpp_mov<0x1B>(v);   // lane0: o

            float t2  = v * g0;            // 2l2e*(i*g)  (lane0)
            float p2o = -2.f * oo;         // off-path for the tail fma
            C = __builtin_fmaf(w, C, t2);  // C = f*C + 2l2e*(i*g)
            float e2 = EXP2F(C);           // = e^(2c)
            float rr = __builtin_amdgcn_rcpf(1.f + e2);
            float hn = __builtin_fmaf(p2o, rr, oo);  // o*tanh(c)

            if (kc == 0) {
                hbuf[1 - p][u] = hn;
                // fire-and-forget global store; vmcnt is NOT drained by the
                // lgkm-only barrier, so this never sits on the critical path.
                hp[(size_t)(ch * CH + tt) * NH] = hn;
            }
            wg_barrier_lgkm();
        }

#pragma unroll
        for (int tt = 0; tt < CH; ++tt) xq[tt] = xn[tt];
    }
}

// ---------------- Kernel 3: output projection out[t] = W_out @ h_t + b_out ----
__global__ __launch_bounds__(256) void outproj_kernel(
    const float* __restrict__ hout, const float* __restrict__ W_out,
    const float* __restrict__ b_out, float* __restrict__ out)
{
    int idx = blockIdx.x * blockDim.x + threadIdx.x;   // T*2
    if (idx >= T_STEPS * 2) return;
    int t = idx >> 1, o = idx & 1;
    const float* hr = hout + (size_t)t * NH;
    const float* wr = W_out + o * NH;
    float s = b_out[o];
#pragma unroll
    for (int j = 0; j < NH; ++j) s += hr[j] * wr[j];
    out[t * 2 + o] = s;
}

extern "C" void kernel_launch(void* const* d_in, const int* in_sizes, int n_in,
                              void* d_out, int out_size, void* d_ws, size_t ws_size,
                              hipStream_t stream) {
    const float* x     = (const float*)d_in[0];
    const float* W_ih  = (const float*)d_in[1];
    const float* W_hh  = (const float*)d_in[2];
    const float* b_ih  = (const float*)d_in[3];
    const float* b_hh  = (const float*)d_in[4];
    const float* W_out = (const float*)d_in[5];
    const float* b_out = (const float*)d_in[6];
    float* out = (float*)d_out;

    // workspace layout: xp (T*256 floats) | hout (T*64 floats)  = 2.5 MB
    float* xp   = (float*)d_ws;
    float* hout = xp + (size_t)T_STEPS * NG;

    xproj_kernel<<<T_STEPS / XT, 256, 0, stream>>>(x, W_ih, b_ih, b_hh, xp);
    lstm_scan_kernel<<<1, 256, 0, stream>>>(W_hh, xp, hout);
    outproj_kernel<<<(T_STEPS * 2 + 255) / 256, 256, 0, stream>>>(hout, W_out, b_out, out);
}